// Round 14
// baseline (272.874 us; speedup 1.0000x reference)
//
#include <hip/hip_runtime.h>

// Within-bench A/B/C (one launch, three dispatches, per-dispatch rocprof rows):
//   1) k_cand   — per-wave LDS redistribution (coalesced + barrier-free candidate)
//   2) k_copy   — pure float4 copy state->out (environment-cap control; wrong
//                 output, immediately overwritten)
//   3) k_anchor — R6's measured-71us strided kernel, runs last -> correct d_out.
// All three full-size. Measured record: R4 77us | R6 71us | R7 74us | R8 82us,
// all ~2.3-2.5 TB/s vs fillBuffer 6.6 TB/s. k_copy decides structure-vs-env cap.

namespace {
constexpr float kL0  = 0.4f;
constexpr float kL1  = 0.08f;
constexpr float kYLo = 0.0f;
constexpr float kYHi = 2.0f;
constexpr float kFar = 10.0f;
constexpr int COLS = 7;
constexpr int TPB  = 256;
// candidate:
constexpr int WPB  = 4;
constexpr int RPW  = 256;
constexpr int F4PW = RPW * COLS / 4;   // 448
// anchor:
constexpr int UNR  = 4;
}

typedef float f4 __attribute__((ext_vector_type(4)));
typedef float f4u __attribute__((ext_vector_type(4), aligned(4)));
typedef float f2u __attribute__((ext_vector_type(2), aligned(4)));

__device__ __forceinline__ void sincos_small(float ax, float& s, float& c) {
    const float x2 = ax * ax;
    s = ax * (1.0f + x2 * (-1.6666667e-1f + x2 * (8.3333333e-3f
             + x2 * (-1.9841270e-4f))));
    c = 1.0f + x2 * (-0.5f + x2 * (4.1666667e-2f + x2 * (-1.3888889e-3f
             + x2 * (2.4801587e-5f))));
}

__device__ __forceinline__ void compute_row(
    float cx, float cy, float vx, float vy, float phi,
    const float* bxl, const float* bxr, const float* byb, const float* byt,
    float* o)
{
    float sa, ca;
    sincos_small(fabsf(phi), sa, ca);   // cos(phi) == cos(|phi|)
    const float half_x = ca * (kL0 * 0.5f) + sa * (kL1 * 0.5f);
    const float half_y = sa * (kL0 * 0.5f) + ca * (kL1 * 0.5f);

    float up   = kYHi - cy - half_y;
    float down = cy - kYLo - half_y;
    float d1 = kFar, d2 = kFar;
    const float lo = cx - half_x;
    const float hi = cx + half_x;
    const float ylo_e = cy - half_y;
    const float yhi_e = cy + half_y;

    #pragma unroll
    for (int i = 0; i < 3; ++i) {
        const bool x_in = (bxl[i] <= hi && bxl[i] >= lo) ||
                          (bxr[i] <= hi && bxr[i] >= lo);
        if (x_in) {
            up   = byt[i] - cy - half_y;
            down = cy - byb[i] - half_y;
        }
        const bool passed = hi < bxl[i];
        const float dist  = bxl[i] - cx - half_x;
        const bool y1_out = (ylo_e < byb[i]) || (ylo_e > byt[i]);
        const bool y2_out = (yhi_e > byt[i]) || (yhi_e < byb[i]);
        if (passed && y1_out && d1 == kFar) d1 = dist;
        if (passed && y2_out && d2 == kFar) d2 = dist;
    }

    o[0] = d1; o[1] = d2; o[2] = up; o[3] = down;
    o[4] = vx; o[5] = vy; o[6] = phi;
}

__device__ __forceinline__ void load_blocks(
    const float* __restrict__ blocks,
    float* bxl, float* bxr, float* byb, float* byt)
{
    #pragma unroll
    for (int i = 0; i < 3; ++i) {
        const float x  = blocks[i * 4 + 0];
        const float y  = blocks[i * 4 + 1];
        const float w2 = 0.5f * blocks[i * 4 + 2];
        const float h2 = 0.5f * blocks[i * 4 + 3];
        bxl[i] = x - w2;
        bxr[i] = x + w2;
        byb[i] = y - h2;
        byt[i] = y + h2;
    }
}

// ---------- 1) candidate: per-wave LDS redistribution ----------
__global__ __launch_bounds__(TPB) void k_cand(
    const float* __restrict__ state,
    const float* __restrict__ blocks,
    float* __restrict__ out,
    int nrows)
{
    __shared__ f4 lds[WPB][F4PW];   // 28 KiB

    const int lane = threadIdx.x & 63;
    const int w    = threadIdx.x >> 6;

    float bxl[3], bxr[3], byb[3], byt[3];
    load_blocks(blocks, bxl, bxr, byb, byt);

    const long long gw     = (long long)blockIdx.x * WPB + w;
    const long long nwaves = (long long)gridDim.x * WPB;
    const long long nwt    = (long long)nrows / RPW;

    const f4* in4  = reinterpret_cast<const f4*>(state);
    f4*       out4 = reinterpret_cast<f4*>(out);

    for (long long wt = gw; wt < nwt; wt += nwaves) {
        const long long b4 = wt * F4PW;

        f4 q[7];
        #pragma unroll
        for (int j = 0; j < 7; ++j) q[j] = in4[b4 + j * 64 + lane];
        #pragma unroll
        for (int j = 0; j < 7; ++j) lds[w][j * 64 + lane] = q[j];
        asm volatile("s_waitcnt lgkmcnt(0)" ::: "memory");   // intra-wave only
        __builtin_amdgcn_sched_barrier(0);

        f4 r[7];
        #pragma unroll
        for (int k = 0; k < 7; ++k) r[k] = lds[w][lane * 7 + k];

        float* fs = reinterpret_cast<float*>(r);
        #pragma unroll
        for (int rr = 0; rr < 4; ++rr) {
            float* s = fs + rr * 7;
            compute_row(s[0], s[1], s[2], s[3], s[4], bxl, bxr, byb, byt, s);
        }

        #pragma unroll
        for (int k = 0; k < 7; ++k) lds[w][lane * 7 + k] = r[k];
        asm volatile("s_waitcnt lgkmcnt(0)" ::: "memory");
        __builtin_amdgcn_sched_barrier(0);

        #pragma unroll
        for (int j = 0; j < 7; ++j) q[j] = lds[w][j * 64 + lane];
        #pragma unroll
        for (int j = 0; j < 7; ++j) out4[b4 + j * 64 + lane] = q[j];
    }

    // tail (empty at benched shape)
    const long long tail0 = nwt * RPW;
    const long long gtid  = (long long)blockIdx.x * TPB + threadIdx.x;
    const long long nth   = (long long)gridDim.x * TPB;
    for (long long r = tail0 + gtid; r < nrows; r += nth) {
        const float* p = state + r * COLS;
        float orow[7];
        compute_row(p[0], p[1], p[2], p[3], p[4], bxl, bxr, byb, byt, orow);
        float* o = out + r * COLS;
        #pragma unroll
        for (int c = 0; c < 7; ++c) o[c] = orow[c];
    }
}

// ---------- 2) control: pure float4 copy (m13 pattern) ----------
__global__ __launch_bounds__(TPB) void k_copy(
    const float* __restrict__ src,
    float* __restrict__ dst,
    long long n4)
{
    const long long gtid = (long long)blockIdx.x * TPB + threadIdx.x;
    const long long nth  = (long long)gridDim.x * TPB;
    const f4* s4 = reinterpret_cast<const f4*>(src);
    f4*       d4 = reinterpret_cast<f4*>(dst);
    for (long long i = gtid; i < n4; i += nth) d4[i] = s4[i];
}

// ---------- 3) anchor: R6's strided UNR=4 (measured 71us) ----------
__global__ __launch_bounds__(TPB) void k_anchor(
    const float* __restrict__ state,
    const float* __restrict__ blocks,
    float* __restrict__ out,
    int nrows)
{
    const int gtid = blockIdx.x * TPB + threadIdx.x;
    const int NT   = gridDim.x * TPB;

    float bxl[3], bxr[3], byb[3], byt[3];
    load_blocks(blocks, bxl, bxr, byb, byt);

    for (long long r0 = gtid; r0 < nrows; r0 += (long long)NT * UNR) {
        f4u   a[UNR];
        float ph[UNR];
        #pragma unroll
        for (int k = 0; k < UNR; ++k) {
            const long long r = r0 + (long long)k * NT;
            if (r < nrows) {
                const float* p = state + r * COLS;
                a[k]  = *reinterpret_cast<const f4u*>(p);
                ph[k] = p[4];
            }
        }

        #pragma unroll
        for (int k = 0; k < UNR; ++k) {
            const long long r = r0 + (long long)k * NT;
            if (r >= nrows) continue;
            float orow[7];
            compute_row(a[k][0], a[k][1], a[k][2], a[k][3], ph[k],
                        bxl, bxr, byb, byt, orow);
            float* o = out + r * COLS;
            f4u o4 = {orow[0], orow[1], orow[2], orow[3]};
            f2u o2 = {orow[4], orow[5]};
            *reinterpret_cast<f4u*>(o)     = o4;
            *reinterpret_cast<f2u*>(o + 4) = o2;
            o[6] = orow[6];
        }
    }
}

extern "C" void kernel_launch(void* const* d_in, const int* in_sizes, int n_in,
                              void* d_out, int out_size, void* d_ws, size_t ws_size,
                              hipStream_t stream) {
    const float* state  = (const float*)d_in[0];
    const float* blocks = (const float*)d_in[1];
    float* out = (float*)d_out;

    const int nrows = in_sizes[0] / COLS;
    const long long ntot = (long long)nrows * COLS;

    // 1) candidate (cold, standard conditions)
    {
        const long long nwt = (long long)nrows / RPW;
        long long want = (nwt + WPB - 1) / WPB;
        if (want < 1) want = 1;
        const int grid = (int)(want > 2048 ? 2048 : want);
        k_cand<<<grid, TPB, 0, stream>>>(state, blocks, out, nrows);
    }

    // 2) copy control (output wrong; overwritten by anchor below)
    {
        const long long n4 = ntot / 4;   // benched shape: exact
        long long want = (n4 + TPB - 1) / TPB;
        const int grid = (int)(want < 1 ? 1 : (want > 2048 ? 2048 : want));
        k_copy<<<grid, TPB, 0, stream>>>(state, out, n4);
        // scalar remainder (none at benched shape) handled by anchor anyway.
    }

    // 3) anchor (correct final output)
    {
        const long long per = (long long)TPB * UNR;
        long long want = ((long long)nrows + per - 1) / per;
        const int grid = (int)(want < 1 ? 1 : (want > 4096 ? 4096 : want));
        k_anchor<<<grid, TPB, 0, stream>>>(state, blocks, out, nrows);
    }
}